// Round 2
// baseline (1354.763 us; speedup 1.0000x reference)
//
#include <hip/hip_runtime.h>
#include <math.h>

constexpr double EPS = 1e-5;
constexpr int BTOT = 131072;
constexpr int SPW = 4;            // samples per wave
constexpr int WAVES = 2;          // waves per block
constexpr int SBLK = SPW * WAVES; // samples per block

// ---- wave-wide sum of 3 doubles (64 lanes) ----
__device__ __forceinline__ void wave_sum3_d(double& a, double& b, double& c) {
#pragma unroll
  for (int o = 32; o > 0; o >>= 1) {
    a += __shfl_xor(a, o, 64);
    b += __shfl_xor(b, o, 64);
    c += __shfl_xor(c, o, 64);
  }
}

// ---- 2nd-order jet of tanh (fp64 arithmetic, u from accurate tanhf) ----
__device__ __forceinline__ void tanh_jet_d(double z, double z1, double z2,
                                           double& u, double& u1, double& u2) {
  u = (double)tanhf((float)z);         // ~1 ulp fp32, good at small z
  double d = (1.0 - u) * (1.0 + u);    // 1 - u^2
  u1 = d * z1;
  u2 = d * (z2 - 2.0 * u * z1 * z1);
}

// ---- tanh + LayerNorm on jets (fp64), store to LDS row ----
template<int CH>
__device__ __forceinline__ void act_ln_store_d(
    const double (&z0)[CH], const double (&z1)[CH], const double (&z2)[CH],
    const float* __restrict__ g, const float* __restrict__ be,
    int lane, double (&row)[3][128]) {
  constexpr int N = 64 * CH;
  constexpr double invN = 1.0 / (double)N;
  double u[CH], u1[CH], u2[CH];
  double s0 = 0.0, s1 = 0.0, s2 = 0.0;
#pragma unroll
  for (int c = 0; c < CH; ++c) {
    tanh_jet_d(z0[c], z1[c], z2[c], u[c], u1[c], u2[c]);
    s0 += u[c]; s1 += u1[c]; s2 += u2[c];
  }
  wave_sum3_d(s0, s1, s2);
  double mu = s0 * invN, mu1 = s1 * invN, mu2 = s2 * invN;
  double cc[CH], d1[CH], d2[CH];
  double t0 = 0.0, t1 = 0.0, t2 = 0.0;
#pragma unroll
  for (int c = 0; c < CH; ++c) {
    cc[c] = u[c] - mu; d1[c] = u1[c] - mu1; d2[c] = u2[c] - mu2;
    t0 += cc[c] * cc[c];
    t1 += cc[c] * d1[c];
    t2 += d1[c] * d1[c] + cc[c] * d2[c];
  }
  wave_sum3_d(t0, t1, t2);
  double var  = t0 * invN;
  double var1 = 2.0 * t1 * invN;
  double var2 = 2.0 * t2 * invN;
  double s  = 1.0 / sqrt(var + EPS);
  double s3 = s * s * s;
  double sp  = -0.5 * s3 * var1;                                   // ds/dt
  double spp = 0.75 * s3 * s * s * var1 * var1 - 0.5 * s3 * var2;  // d2s/dt2
#pragma unroll
  for (int c = 0; c < CH; ++c) {
    int ch = lane + 64 * c;
    double gg = (double)g[ch], bb = (double)be[ch];
    row[0][ch] = cc[c] * s * gg + bb;
    row[1][ch] = (d1[c] * s + cc[c] * sp) * gg;
    row[2][ch] = (d2[c] * s + 2.0 * d1[c] * sp + cc[c] * spp) * gg;
  }
}

// ---- dense K->64*CH + tanh + LN, jets, fp64 ----
template<int K, int CH>
__device__ __forceinline__ void dense_tanh_ln_d(
    const float* __restrict__ W, const float* __restrict__ bias,
    const float* __restrict__ g, const float* __restrict__ be,
    const double (*__restrict__ hin)[3][128], double (*__restrict__ hout)[3][128],
    int lane) {
  double acc[SPW][3][CH];
#pragma unroll
  for (int i = 0; i < SPW; ++i)
#pragma unroll
    for (int j = 0; j < 3; ++j)
#pragma unroll
      for (int c = 0; c < CH; ++c) acc[i][j][c] = 0.0;

  const float* Wr0 = W + lane * K;
  const float* Wr1 = W + (lane + 64) * K;   // unused when CH==1

#pragma unroll 4
  for (int k = 0; k < K; ++k) {
    double wv[CH];
    wv[0] = (double)Wr0[k];
    if (CH == 2) wv[1] = (double)Wr1[k];
#pragma unroll
    for (int i = 0; i < SPW; ++i) {
      double h0 = hin[i][0][k];
      double h1 = hin[i][1][k];
      double h2 = hin[i][2][k];
#pragma unroll
      for (int c = 0; c < CH; ++c) {
        acc[i][0][c] = fma(wv[c], h0, acc[i][0][c]);
        acc[i][1][c] = fma(wv[c], h1, acc[i][1][c]);
        acc[i][2][c] = fma(wv[c], h2, acc[i][2][c]);
      }
    }
  }

#pragma unroll
  for (int i = 0; i < SPW; ++i) {
    double z0[CH], z1[CH], z2[CH];
#pragma unroll
    for (int c = 0; c < CH; ++c) {
      int ch = lane + 64 * c;
      z0[c] = acc[i][0][c] + (double)bias[ch];
      z1[c] = acc[i][1][c];
      z2[c] = acc[i][2][c];
    }
    act_ln_store_d<CH>(z0, z1, z2, g, be, lane, hout[i]);
  }
}

__global__ void __launch_bounds__(WAVES * 64)
pinn_kernel(const float* __restrict__ t,
            const float* __restrict__ W0, const float* __restrict__ b0,
            const float* __restrict__ g0, const float* __restrict__ be0,
            const float* __restrict__ W1, const float* __restrict__ b1,
            const float* __restrict__ g1, const float* __restrict__ be1,
            const float* __restrict__ W2, const float* __restrict__ b2,
            const float* __restrict__ g2, const float* __restrict__ be2,
            const float* __restrict__ W3, const float* __restrict__ b3,
            const float* __restrict__ g3, const float* __restrict__ be3,
            const float* __restrict__ W4, const float* __restrict__ b4,
            float* __restrict__ out) {
  __shared__ double h[2][SBLK][3][128];
  const int tid = threadIdx.x;
  const int lane = tid & 63;
  const int wv = tid >> 6;
  const int sbase = blockIdx.x * SBLK + wv * SPW;

  double (*bufA)[3][128] = &h[0][wv * SPW];
  double (*bufB)[3][128] = &h[1][wv * SPW];

  // ---- layer 0: 1 -> 64, tanh, LN. jets of input t: (t, 1, 0) ----
  {
    double w0v = (double)W0[lane];
    double b0v = (double)b0[lane];
#pragma unroll
    for (int i = 0; i < SPW; ++i) {
      double ts = (double)t[sbase + i];
      double z0[1] = { fma(w0v, ts, b0v) };
      double z1[1] = { w0v };
      double z2[1] = { 0.0 };
      act_ln_store_d<1>(z0, z1, z2, g0, be0, lane, bufA[i]);
    }
  }

  dense_tanh_ln_d<64, 2>(W1, b1, g1, be1, bufA, bufB, lane);
  dense_tanh_ln_d<128, 2>(W2, b2, g2, be2, bufB, bufA, lane);
  dense_tanh_ln_d<128, 1>(W3, b3, g3, be3, bufA, bufB, lane);

  // ---- layer 4: 64 -> 1 ----
  {
    double w4v = (double)W4[lane];
    double b4v = (double)b4[0];
#pragma unroll
    for (int i = 0; i < SPW; ++i) {
      double x = w4v * bufB[i][0][lane];
      double v = w4v * bufB[i][1][lane];
      double a = w4v * bufB[i][2][lane];
      wave_sum3_d(x, v, a);
      if (lane == 0) {
        int s = sbase + i;
        out[s]            = (float)(x + b4v);
        out[BTOT + s]     = (float)v;
        out[2 * BTOT + s] = (float)a;
      }
    }
  }
}

extern "C" void kernel_launch(void* const* d_in, const int* in_sizes, int n_in,
                              void* d_out, int out_size, void* d_ws, size_t ws_size,
                              hipStream_t stream) {
  const float* t   = (const float*)d_in[0];
  const float* W0  = (const float*)d_in[1];
  const float* b0  = (const float*)d_in[2];
  const float* g0  = (const float*)d_in[3];
  const float* be0 = (const float*)d_in[4];
  const float* W1  = (const float*)d_in[5];
  const float* b1  = (const float*)d_in[6];
  const float* g1  = (const float*)d_in[7];
  const float* be1 = (const float*)d_in[8];
  const float* W2  = (const float*)d_in[9];
  const float* b2  = (const float*)d_in[10];
  const float* g2  = (const float*)d_in[11];
  const float* be2 = (const float*)d_in[12];
  const float* W3  = (const float*)d_in[13];
  const float* b3  = (const float*)d_in[14];
  const float* g3  = (const float*)d_in[15];
  const float* be3 = (const float*)d_in[16];
  const float* W4  = (const float*)d_in[17];
  const float* b4  = (const float*)d_in[18];
  float* out = (float*)d_out;

  dim3 grid(BTOT / SBLK);
  dim3 block(WAVES * 64);
  hipLaunchKernelGGL(pinn_kernel, grid, block, 0, stream,
                     t, W0, b0, g0, be0, W1, b1, g1, be1,
                     W2, b2, g2, be2, W3, b3, g3, be3, W4, b4, out);
}

// Round 4
// 915.950 us; speedup vs baseline: 1.4791x; 1.4791x over previous
//
#include <hip/hip_runtime.h>
#include <math.h>

constexpr double EPS = 1e-5;
constexpr int BTOT = 131072;
constexpr int SPW = 4;            // samples per wave
constexpr int WAVES = 2;          // waves per block
constexpr int SBLK = SPW * WAVES; // samples per block

// ---- wave-wide sum of 3 doubles (64 lanes) ----
__device__ __forceinline__ void wave_sum3_d(double& a, double& b, double& c) {
#pragma unroll
  for (int o = 32; o > 0; o >>= 1) {
    a += __shfl_xor(a, o, 64);
    b += __shfl_xor(b, o, 64);
    c += __shfl_xor(c, o, 64);
  }
}

// ---- tanh + LayerNorm on jets (fp64 chain), store to LDS row (fp32) ----
// USE_F64_TANH: layer 0 sits in the eps-dominated LN regime -> full fp64 tanh.
template<int CH, bool USE_F64_TANH>
__device__ __forceinline__ void act_ln_store(
    const double (&z0)[CH], const double (&z1)[CH], const double (&z2)[CH],
    const float* __restrict__ g, const float* __restrict__ be,
    int lane, float (&row)[3][128]) {
  constexpr int N = 64 * CH;
  constexpr double invN = 1.0 / (double)N;
  double u[CH], u1[CH], u2[CH];
  double s0 = 0.0, s1 = 0.0, s2 = 0.0;
#pragma unroll
  for (int c = 0; c < CH; ++c) {
    double uu = USE_F64_TANH ? tanh(z0[c]) : (double)tanhf((float)z0[c]);
    double d = (1.0 - uu) * (1.0 + uu);    // 1 - u^2
    u[c]  = uu;
    u1[c] = d * z1[c];
    u2[c] = d * (z2[c] - 2.0 * uu * z1[c] * z1[c]);
    s0 += u[c]; s1 += u1[c]; s2 += u2[c];
  }
  wave_sum3_d(s0, s1, s2);
  double mu = s0 * invN, mu1 = s1 * invN, mu2 = s2 * invN;
  double cc[CH], d1[CH], d2[CH];
  double t0 = 0.0, t1 = 0.0, t2 = 0.0;
#pragma unroll
  for (int c = 0; c < CH; ++c) {
    cc[c] = u[c] - mu; d1[c] = u1[c] - mu1; d2[c] = u2[c] - mu2;
    t0 += cc[c] * cc[c];
    t1 += cc[c] * d1[c];
    t2 += d1[c] * d1[c] + cc[c] * d2[c];
  }
  wave_sum3_d(t0, t1, t2);
  double var  = t0 * invN;
  double var1 = 2.0 * t1 * invN;
  double var2 = 2.0 * t2 * invN;
  double s  = 1.0 / sqrt(var + EPS);
  double s3 = s * s * s;
  double sp  = -0.5 * s3 * var1;                                   // ds/dt
  double spp = 0.75 * s3 * s * s * var1 * var1 - 0.5 * s3 * var2;  // d2s/dt2
#pragma unroll
  for (int c = 0; c < CH; ++c) {
    int ch = lane + 64 * c;
    double gg = (double)g[ch], bb = (double)be[ch];
    row[0][ch] = (float)(cc[c] * s * gg + bb);
    row[1][ch] = (float)((d1[c] * s + cc[c] * sp) * gg);
    row[2][ch] = (float)((d2[c] * s + 2.0 * d1[c] * sp + cc[c] * spp) * gg);
  }
}

// ---- dense K->64*CH (fp32 matvec) + tanh + LN (fp64 chain) ----
template<int K, int CH>
__device__ __forceinline__ void dense_tanh_ln(
    const float* __restrict__ W, const float* __restrict__ bias,
    const float* __restrict__ g, const float* __restrict__ be,
    const float (*__restrict__ hin)[3][128], float (*__restrict__ hout)[3][128],
    int lane) {
  float acc[SPW][3][CH];
#pragma unroll
  for (int i = 0; i < SPW; ++i)
#pragma unroll
    for (int j = 0; j < 3; ++j)
#pragma unroll
      for (int c = 0; c < CH; ++c) acc[i][j][c] = 0.f;

  const float* Wr0 = W + lane * K;
  const float* Wr1 = W + (lane + 64) * K;   // unused when CH==1

#pragma unroll 4
  for (int k = 0; k < K; ++k) {
    float wv[CH];
    wv[0] = Wr0[k];
    if (CH == 2) wv[1] = Wr1[k];
#pragma unroll
    for (int i = 0; i < SPW; ++i) {
      float h0 = hin[i][0][k];
      float h1 = hin[i][1][k];
      float h2 = hin[i][2][k];
#pragma unroll
      for (int c = 0; c < CH; ++c) {
        acc[i][0][c] = fmaf(wv[c], h0, acc[i][0][c]);
        acc[i][1][c] = fmaf(wv[c], h1, acc[i][1][c]);
        acc[i][2][c] = fmaf(wv[c], h2, acc[i][2][c]);
      }
    }
  }

#pragma unroll
  for (int i = 0; i < SPW; ++i) {
    double z0[CH], z1[CH], z2[CH];
#pragma unroll
    for (int c = 0; c < CH; ++c) {
      int ch = lane + 64 * c;
      z0[c] = (double)acc[i][0][c] + (double)bias[ch];
      z1[c] = (double)acc[i][1][c];
      z2[c] = (double)acc[i][2][c];
    }
    act_ln_store<CH, false>(z0, z1, z2, g, be, lane, hout[i]);
  }
}

__global__ void __launch_bounds__(WAVES * 64)
pinn_kernel(const float* __restrict__ t,
            const float* __restrict__ W0, const float* __restrict__ b0,
            const float* __restrict__ g0, const float* __restrict__ be0,
            const float* __restrict__ W1, const float* __restrict__ b1,
            const float* __restrict__ g1, const float* __restrict__ be1,
            const float* __restrict__ W2, const float* __restrict__ b2,
            const float* __restrict__ g2, const float* __restrict__ be2,
            const float* __restrict__ W3, const float* __restrict__ b3,
            const float* __restrict__ g3, const float* __restrict__ be3,
            const float* __restrict__ W4, const float* __restrict__ b4,
            float* __restrict__ out) {
  __shared__ float h[2][SBLK][3][128];
  const int tid = threadIdx.x;
  const int lane = tid & 63;
  const int wv = tid >> 6;
  const int sbase = blockIdx.x * SBLK + wv * SPW;

  float (*bufA)[3][128] = &h[0][wv * SPW];
  float (*bufB)[3][128] = &h[1][wv * SPW];

  // ---- layer 0: 1 -> 64, tanh, LN — full fp64 (eps-dominated LN regime) ----
  {
    double w0v = (double)W0[lane];
    double b0v = (double)b0[lane];
#pragma unroll
    for (int i = 0; i < SPW; ++i) {
      double ts = (double)t[sbase + i];
      double z0[1] = { fma(w0v, ts, b0v) };
      double z1[1] = { w0v };
      double z2[1] = { 0.0 };
      act_ln_store<1, true>(z0, z1, z2, g0, be0, lane, bufA[i]);
    }
  }

  dense_tanh_ln<64, 2>(W1, b1, g1, be1, bufA, bufB, lane);
  dense_tanh_ln<128, 2>(W2, b2, g2, be2, bufB, bufA, lane);
  dense_tanh_ln<128, 1>(W3, b3, g3, be3, bufA, bufB, lane);

  // ---- layer 4: 64 -> 1 (fp64, cheap) ----
  {
    double w4v = (double)W4[lane];
    double b4v = (double)b4[0];
#pragma unroll
    for (int i = 0; i < SPW; ++i) {
      double x = w4v * (double)bufB[i][0][lane];
      double v = w4v * (double)bufB[i][1][lane];
      double a = w4v * (double)bufB[i][2][lane];
      wave_sum3_d(x, v, a);
      if (lane == 0) {
        int s = sbase + i;
        out[s]            = (float)(x + b4v);
        out[BTOT + s]     = (float)v;
        out[2 * BTOT + s] = (float)a;
      }
    }
  }
}

extern "C" void kernel_launch(void* const* d_in, const int* in_sizes, int n_in,
                              void* d_out, int out_size, void* d_ws, size_t ws_size,
                              hipStream_t stream) {
  const float* t   = (const float*)d_in[0];
  const float* W0  = (const float*)d_in[1];
  const float* b0  = (const float*)d_in[2];
  const float* g0  = (const float*)d_in[3];
  const float* be0 = (const float*)d_in[4];
  const float* W1  = (const float*)d_in[5];
  const float* b1  = (const float*)d_in[6];
  const float* g1  = (const float*)d_in[7];
  const float* be1 = (const float*)d_in[8];
  const float* W2  = (const float*)d_in[9];
  const float* b2  = (const float*)d_in[10];
  const float* g2  = (const float*)d_in[11];
  const float* be2 = (const float*)d_in[12];
  const float* W3  = (const float*)d_in[13];
  const float* b3  = (const float*)d_in[14];
  const float* g3  = (const float*)d_in[15];
  const float* be3 = (const float*)d_in[16];
  const float* W4  = (const float*)d_in[17];
  const float* b4  = (const float*)d_in[18];
  float* out = (float*)d_out;

  dim3 grid(BTOT / SBLK);
  dim3 block(WAVES * 64);
  hipLaunchKernelGGL(pinn_kernel, grid, block, 0, stream,
                     t, W0, b0, g0, be0, W1, b1, g1, be1,
                     W2, b2, g2, be2, W3, b3, g3, be3, W4, b4, out);
}

// Round 8
// 715.507 us; speedup vs baseline: 1.8934x; 1.2801x over previous
//
#include <hip/hip_runtime.h>
#include <math.h>

constexpr float  EPSf = 1e-5f;
constexpr double EPSd = 1e-5;
constexpr int BTOT = 131072;
constexpr int SPW = 4;            // samples per wave
constexpr int WAVES = 2;          // waves per block
constexpr int SBLK = SPW * WAVES; // samples per block

// ---- wave-wide sum of 3 floats (64 lanes) ----
__device__ __forceinline__ void wave_sum3_f(float& a, float& b, float& c) {
#pragma unroll
  for (int o = 32; o > 0; o >>= 1) {
    a += __shfl_xor(a, o, 64);
    b += __shfl_xor(b, o, 64);
    c += __shfl_xor(c, o, 64);
  }
}
__device__ __forceinline__ void wave_sum3_d(double& a, double& b, double& c) {
#pragma unroll
  for (int o = 32; o > 0; o >>= 1) {
    a += __shfl_xor(a, o, 64);
    b += __shfl_xor(b, o, 64);
    c += __shfl_xor(c, o, 64);
  }
}

// ---- tanh + LayerNorm on jets, store to LDS row ----
// F64CHAIN: layer 0 sits in the eps-dominated LN regime -> fp64 scalar chain.
// tanhf everywhere (1-ulp RELATIVE error; the round-0 failure was __expf's
// absolute error at small z, not fp32 per se).
template<int CH, bool F64CHAIN>
__device__ __forceinline__ void act_ln_store(
    const float (&z0)[CH], const float (&z1)[CH], const float (&z2)[CH],
    const float (&gv)[CH], const float (&bev)[CH],
    int lane, float (&row)[3][128]) {
  constexpr int N = 64 * CH;
  if constexpr (F64CHAIN) {
    constexpr double invN = 1.0 / (double)N;
    double u[CH], u1[CH], u2[CH];
    double s0 = 0.0, s1 = 0.0, s2 = 0.0;
#pragma unroll
    for (int c = 0; c < CH; ++c) {
      double uu = (double)tanhf(z0[c]);
      double d = (1.0 - uu) * (1.0 + uu);
      double zz1 = (double)z1[c];
      u[c] = uu;
      u1[c] = d * zz1;
      u2[c] = d * ((double)z2[c] - 2.0 * uu * zz1 * zz1);
      s0 += u[c]; s1 += u1[c]; s2 += u2[c];
    }
    wave_sum3_d(s0, s1, s2);
    double mu = s0 * invN, mu1 = s1 * invN, mu2 = s2 * invN;
    double cc[CH], d1[CH], d2[CH];
    double t0 = 0.0, t1 = 0.0, t2 = 0.0;
#pragma unroll
    for (int c = 0; c < CH; ++c) {
      cc[c] = u[c] - mu; d1[c] = u1[c] - mu1; d2[c] = u2[c] - mu2;
      t0 += cc[c] * cc[c];
      t1 += cc[c] * d1[c];
      t2 += d1[c] * d1[c] + cc[c] * d2[c];
    }
    wave_sum3_d(t0, t1, t2);
    double var  = t0 * invN;
    double var1 = 2.0 * t1 * invN;
    double var2 = 2.0 * t2 * invN;
    double s  = 1.0 / sqrt(var + EPSd);
    double s3 = s * s * s;
    double sp  = -0.5 * s3 * var1;
    double spp = 0.75 * s3 * s * s * var1 * var1 - 0.5 * s3 * var2;
#pragma unroll
    for (int c = 0; c < CH; ++c) {
      int ch = lane + 64 * c;
      row[0][ch] = (float)(cc[c] * s * (double)gv[c] + (double)bev[c]);
      row[1][ch] = (float)((d1[c] * s + cc[c] * sp) * (double)gv[c]);
      row[2][ch] = (float)((d2[c] * s + 2.0 * d1[c] * sp + cc[c] * spp) * (double)gv[c]);
    }
  } else {
    constexpr float invN = 1.f / (float)N;
    float u[CH], u1[CH], u2[CH];
    float s0 = 0.f, s1 = 0.f, s2 = 0.f;
#pragma unroll
    for (int c = 0; c < CH; ++c) {
      float uu = tanhf(z0[c]);
      float d = (1.f - uu) * (1.f + uu);
      u[c] = uu;
      u1[c] = d * z1[c];
      u2[c] = d * (z2[c] - 2.f * uu * z1[c] * z1[c]);
      s0 += u[c]; s1 += u1[c]; s2 += u2[c];
    }
    wave_sum3_f(s0, s1, s2);
    float mu = s0 * invN, mu1 = s1 * invN, mu2 = s2 * invN;
    float cc[CH], d1[CH], d2[CH];
    float t0 = 0.f, t1 = 0.f, t2 = 0.f;
#pragma unroll
    for (int c = 0; c < CH; ++c) {
      cc[c] = u[c] - mu; d1[c] = u1[c] - mu1; d2[c] = u2[c] - mu2;
      t0 += cc[c] * cc[c];
      t1 += cc[c] * d1[c];
      t2 += d1[c] * d1[c] + cc[c] * d2[c];
    }
    wave_sum3_f(t0, t1, t2);
    float var  = t0 * invN;
    float var1 = 2.f * t1 * invN;
    float var2 = 2.f * t2 * invN;
    float s  = 1.f / sqrtf(var + EPSf);
    float s3 = s * s * s;
    float sp  = -0.5f * s3 * var1;
    float spp = 0.75f * s3 * s * s * var1 * var1 - 0.5f * s3 * var2;
#pragma unroll
    for (int c = 0; c < CH; ++c) {
      int ch = lane + 64 * c;
      row[0][ch] = fmaf(cc[c] * s, gv[c], bev[c]);
      row[1][ch] = (d1[c] * s + cc[c] * sp) * gv[c];
      row[2][ch] = (d2[c] * s + 2.f * d1[c] * sp + cc[c] * spp) * gv[c];
    }
  }
}

// ---- dense K->64*CH (fp32 matvec, float4 LDS/global) + tanh + LN ----
template<int K, int CH>
__device__ __forceinline__ void dense_tanh_ln(
    const float* __restrict__ W, const float* __restrict__ bias,
    const float* __restrict__ g, const float* __restrict__ be,
    const float (*__restrict__ hin)[3][128], float (*__restrict__ hout)[3][128],
    int lane) {
  float bv[CH], gv[CH], bev[CH];
#pragma unroll
  for (int c = 0; c < CH; ++c) {
    int ch = lane + 64 * c;
    bv[c] = bias[ch]; gv[c] = g[ch]; bev[c] = be[ch];
  }
  float acc[SPW][3][CH];
#pragma unroll
  for (int i = 0; i < SPW; ++i)
#pragma unroll
    for (int j = 0; j < 3; ++j)
#pragma unroll
      for (int c = 0; c < CH; ++c) acc[i][j][c] = 0.f;

  const float4* Wr0 = (const float4*)(W + lane * K);
  const float4* Wr1 = (const float4*)(W + (lane + 64) * K);  // unused if CH==1

#pragma unroll 4
  for (int kb = 0; kb < K / 4; ++kb) {
    float4 w4[CH];
    w4[0] = Wr0[kb];
    if (CH == 2) w4[1] = Wr1[kb];
    const float* wp[CH];
#pragma unroll
    for (int c = 0; c < CH; ++c) wp[c] = (const float*)&w4[c];
#pragma unroll
    for (int i = 0; i < SPW; ++i) {
      float4 h0 = *(const float4*)&hin[i][0][4 * kb];
      float4 h1 = *(const float4*)&hin[i][1][4 * kb];
      float4 h2 = *(const float4*)&hin[i][2][4 * kb];
      const float* h0p = (const float*)&h0;
      const float* h1p = (const float*)&h1;
      const float* h2p = (const float*)&h2;
#pragma unroll
      for (int kk = 0; kk < 4; ++kk) {
#pragma unroll
        for (int c = 0; c < CH; ++c) {
          float wv = wp[c][kk];
          acc[i][0][c] = fmaf(wv, h0p[kk], acc[i][0][c]);
          acc[i][1][c] = fmaf(wv, h1p[kk], acc[i][1][c]);
          acc[i][2][c] = fmaf(wv, h2p[kk], acc[i][2][c]);
        }
      }
    }
  }

#pragma unroll
  for (int i = 0; i < SPW; ++i) {
    float z0[CH], z1[CH], z2[CH];
#pragma unroll
    for (int c = 0; c < CH; ++c) {
      z0[c] = acc[i][0][c] + bv[c];
      z1[c] = acc[i][1][c];
      z2[c] = acc[i][2][c];
    }
    act_ln_store<CH, false>(z0, z1, z2, gv, bev, lane, hout[i]);
  }
}

__global__ void __launch_bounds__(WAVES * 64)
pinn_kernel(const float* __restrict__ t,
            const float* __restrict__ W0, const float* __restrict__ b0,
            const float* __restrict__ g0, const float* __restrict__ be0,
            const float* __restrict__ W1, const float* __restrict__ b1,
            const float* __restrict__ g1, const float* __restrict__ be1,
            const float* __restrict__ W2, const float* __restrict__ b2,
            const float* __restrict__ g2, const float* __restrict__ be2,
            const float* __restrict__ W3, const float* __restrict__ b3,
            const float* __restrict__ g3, const float* __restrict__ be3,
            const float* __restrict__ W4, const float* __restrict__ b4,
            float* __restrict__ out) {
  __shared__ float h[2][SBLK][3][128];
  const int tid = threadIdx.x;
  const int lane = tid & 63;
  const int wv = tid >> 6;
  const int sbase = blockIdx.x * SBLK + wv * SPW;

  float (*bufA)[3][128] = &h[0][wv * SPW];
  float (*bufB)[3][128] = &h[1][wv * SPW];

  // ---- layer 0: 1 -> 64, tanh, LN — fp64 scalar chain (eps-dominated) ----
  {
    float w0v = W0[lane];
    float b0v = b0[lane];
    float gv[1] = { g0[lane] }, bev[1] = { be0[lane] };
#pragma unroll
    for (int i = 0; i < SPW; ++i) {
      float ts = t[sbase + i];
      float z0[1] = { fmaf(w0v, ts, b0v) };
      float z1[1] = { w0v };
      float z2[1] = { 0.f };
      act_ln_store<1, true>(z0, z1, z2, gv, bev, lane, bufA[i]);
    }
  }

  dense_tanh_ln<64, 2>(W1, b1, g1, be1, bufA, bufB, lane);
  dense_tanh_ln<128, 2>(W2, b2, g2, be2, bufB, bufA, lane);
  dense_tanh_ln<128, 1>(W3, b3, g3, be3, bufA, bufB, lane);

  // ---- layer 4: 64 -> 1 ----
  {
    float w4v = W4[lane];
    float b4v = b4[0];
#pragma unroll
    for (int i = 0; i < SPW; ++i) {
      float x = w4v * bufB[i][0][lane];
      float v = w4v * bufB[i][1][lane];
      float a = w4v * bufB[i][2][lane];
      wave_sum3_f(x, v, a);
      if (lane == 0) {
        int s = sbase + i;
        out[s]            = x + b4v;
        out[BTOT + s]     = v;
        out[2 * BTOT + s] = a;
      }
    }
  }
}

extern "C" void kernel_launch(void* const* d_in, const int* in_sizes, int n_in,
                              void* d_out, int out_size, void* d_ws, size_t ws_size,
                              hipStream_t stream) {
  const float* t   = (const float*)d_in[0];
  const float* W0  = (const float*)d_in[1];
  const float* b0  = (const float*)d_in[2];
  const float* g0  = (const float*)d_in[3];
  const float* be0 = (const float*)d_in[4];
  const float* W1  = (const float*)d_in[5];
  const float* b1  = (const float*)d_in[6];
  const float* g1  = (const float*)d_in[7];
  const float* be1 = (const float*)d_in[8];
  const float* W2  = (const float*)d_in[9];
  const float* b2  = (const float*)d_in[10];
  const float* g2  = (const float*)d_in[11];
  const float* be2 = (const float*)d_in[12];
  const float* W3  = (const float*)d_in[13];
  const float* b3  = (const float*)d_in[14];
  const float* g3  = (const float*)d_in[15];
  const float* be3 = (const float*)d_in[16];
  const float* W4  = (const float*)d_in[17];
  const float* b4  = (const float*)d_in[18];
  float* out = (float*)d_out;

  dim3 grid(BTOT / SBLK);
  dim3 block(WAVES * 64);
  hipLaunchKernelGGL(pinn_kernel, grid, block, 0, stream,
                     t, W0, b0, g0, be0, W1, b1, g1, be1,
                     W2, b2, g2, be2, W3, b3, g3, be3, W4, b4, out);
}